// Round 5
// baseline (646.197 us; speedup 1.0000x reference)
//
#include <hip/hip_runtime.h>
#include <math.h>

#define C_DIM 2048
#define E_DIM 64
#define TB    16        // tokens per block (k_router)
#define KC    128       // k per LDS tile
#define WSTR  132       // w row stride in floats (+4 pad: R1-measured 0 conflicts)

__device__ __forceinline__ float dot16(float4 x0, float4 x1, float4 x2, float4 x3,
                                       float4 w0, float4 w1, float4 w2, float4 w3)
{
    float f;
    f = x0.x * w0.x;
    f = fmaf(x0.y, w0.y, f); f = fmaf(x0.z, w0.z, f); f = fmaf(x0.w, w0.w, f);
    f = fmaf(x1.x, w1.x, f); f = fmaf(x1.y, w1.y, f); f = fmaf(x1.z, w1.z, f);
    f = fmaf(x1.w, w1.w, f);
    f = fmaf(x2.x, w2.x, f); f = fmaf(x2.y, w2.y, f); f = fmaf(x2.z, w2.z, f);
    f = fmaf(x2.w, w2.w, f);
    f = fmaf(x3.x, w3.x, f); f = fmaf(x3.y, w3.y, f); f = fmaf(x3.z, w3.z, f);
    f = fmaf(x3.w, w3.w, f);
    return f;
}

// ---------------- K1: fp32 bulk logits (lane=expert, x wave-uniform) ->
// top-4 candidates -> exact fp64 refine -> top-2 + softmax. -----------------
__launch_bounds__(256, 4)
__global__ void k_router(const float* __restrict__ x, const float* __restrict__ w,
                         int* __restrict__ idx0, int* __restrict__ idx1,
                         float* __restrict__ probs, int N)
{
    __shared__ __align__(16) float ws[E_DIM * WSTR];   // 33.8 KB (w tile only)

    const int tid  = threadIdx.x;
    const int lane = tid & 63;
    const int wid  = __builtin_amdgcn_readfirstlane(tid >> 6);
    const int t0   = blockIdx.x * TB;
    const int tw8  = (wid & 1) * 8;    // wave's 8-token group
    const int kh   = (wid >> 1) * 64;  // wave's k-half within each 128-tile

    float acc[8];
#pragma unroll
    for (int t = 0; t < 8; ++t) acc[t] = 0.0f;

    // wave-uniform x base: all 64 lanes read the same address -> broadcast/scalar
    const float* xbase = x + (size_t)(t0 + tw8) * C_DIM + kh;

    for (int kb = 0; kb < C_DIM; kb += KC) {
        __syncthreads();
        // stage w tile: 64 rows x 128 floats = 2048 float4, 8 per thread
#pragma unroll
        for (int i = 0; i < 8; ++i) {
            int id = tid + 256 * i;
            int r  = id >> 5;
            int g  = id & 31;
            float4 v = *(const float4*)(w + (size_t)r * C_DIM + kb + g * 4);
            *(float4*)(&ws[r * WSTR + g * 4]) = v;
        }
        __syncthreads();

        const float* wk = &ws[lane * WSTR + kh];
        const float* xk = xbase + kb;
#pragma unroll
        for (int s = 0; s < 16; ++s) {      // 16 k-steps of 4
            float4 wf = *(const float4*)(wk + s * 4);
#pragma unroll
            for (int t = 0; t < 8; ++t) {
                float4 xf = *(const float4*)(xk + (size_t)t * C_DIM + s * 4);
                float a = acc[t];
                a = fmaf(xf.x, wf.x, a);
                a = fmaf(xf.y, wf.y, a);
                a = fmaf(xf.z, wf.z, a);
                a = fmaf(xf.w, wf.w, a);
                acc[t] = a;
            }
        }
    }

    // ---- partial logits -> LDS (reuse w-tile memory) ----
    __syncthreads();
    float*  Lh   = (float*)ws;                        // [2][TB][68]
    int*    cand = (int*)(Lh + 2 * TB * 68);          // [TB][4]
    double* dsum = (double*)(cand + TB * 4 + 4);      // [TB*4][4] (align ok: offsets mult of 8)

#pragma unroll
    for (int t = 0; t < 8; ++t)
        Lh[(wid >> 1) * TB * 68 + (tw8 + t) * 68 + lane] = acc[t];
    __syncthreads();

    // ---- top-4 per token: one thread scans its token's 64 logits ----
    if (tid < TB) {
        const float* ra = &Lh[tid * 68];
        const float* rb = &Lh[TB * 68 + tid * 68];
        float v0 = -3e38f, v1 = -3e38f, v2 = -3e38f, v3 = -3e38f;
        int   b0 = 64, b1 = 64, b2 = 64, b3 = 64;
#pragma unroll
        for (int e = 0; e < E_DIM; ++e) {
            float vv = ra[e] + rb[e];
            if (vv > v3) {
                if (vv > v0)      { v3=v2;b3=b2; v2=v1;b2=b1; v1=v0;b1=b0; v0=vv;b0=e; }
                else if (vv > v1) { v3=v2;b3=b2; v2=v1;b2=b1; v1=vv;b1=e; }
                else if (vv > v2) { v3=v2;b3=b2; v2=vv;b2=e; }
                else              { v3=vv;b3=e; }
            }
        }
        cand[tid * 4]     = b0;
        cand[tid * 4 + 1] = b1;
        cand[tid * 4 + 2] = b2;
        cand[tid * 4 + 3] = b3;
    }
    __syncthreads();

    // ---- exact refine: fp32 16-chain + fp64 per 16 (absmax-0 numerics),
    //      256 threads = 16 tokens x 4 cands x 4 k-quarters ----
    {
        int h = tid & 3;            // k-quarter
        int p = tid >> 2;           // 0..63 = t*4 + c
        int t = p >> 2;
        int c = cand[p];
        const float* xp = x + (size_t)(t0 + t) * C_DIM + h * (C_DIM / 4);
        const float* wp = w + (size_t)c * C_DIM + h * (C_DIM / 4);
        double d0 = 0.0, d1 = 0.0;
#pragma unroll 4
        for (int k = 0; k < C_DIM / 4; k += 32) {
            float4 xa[8], wa[8];
#pragma unroll
            for (int m = 0; m < 8; ++m) xa[m] = *(const float4*)(xp + k + 4 * m);
#pragma unroll
            for (int m = 0; m < 8; ++m) wa[m] = *(const float4*)(wp + k + 4 * m);
            d0 += (double)dot16(xa[0], xa[1], xa[2], xa[3], wa[0], wa[1], wa[2], wa[3]);
            d1 += (double)dot16(xa[4], xa[5], xa[6], xa[7], wa[4], wa[5], wa[6], wa[7]);
        }
        dsum[p * 4 + h] = d0 + d1;
    }
    __syncthreads();

    // ---- exact top-2 among candidates (ties: lower expert index) ----
    if (tid < TB) {
        int t = tid;
        double v[4]; int e[4];
#pragma unroll
        for (int c = 0; c < 4; ++c) {
            const double* q = &dsum[(t * 4 + c) * 4];
            v[c] = ((q[0] + q[1]) + q[2]) + q[3];
            e[c] = cand[t * 4 + c];
        }
        int b0 = 0;
#pragma unroll
        for (int c = 1; c < 4; ++c)
            if (v[c] > v[b0] || (v[c] == v[b0] && e[c] < e[b0])) b0 = c;
        int b1 = (b0 == 0) ? 1 : 0;
#pragma unroll
        for (int c = 0; c < 4; ++c) {
            if (c == b0 || c == b1) continue;
            if (v[c] > v[b1] || (v[c] == v[b1] && e[c] < e[b1])) b1 = c;
        }
        int n = t0 + t;
        float p0 = 1.0f / (1.0f + expf((float)(v[b1] - v[b0])));
        idx0[n] = e[b0];
        idx1[n] = e[b1];
        probs[2 * n]     = p0;
        probs[2 * n + 1] = 1.0f - p0;
    }
}

// ---------------- K2: rank scan, 128 blocks x 4 waves, one load round ------
__launch_bounds__(256)
__global__ void k_scan(const int* __restrict__ idx0, const int* __restrict__ idx1,
                       int* __restrict__ r0, int* __restrict__ r1, int N)
{
    const int e    = blockIdx.x >> 1;
    const int pass = blockIdx.x & 1;
    const int tid  = threadIdx.x;
    const int lane = tid & 63;
    const int wid  = tid >> 6;
    __shared__ int cnt[4], cnt0[4];

    const int* idx = pass ? idx1 : idx0;
    int*       r   = pass ? r1   : r0;
    const int  seg = wid * (N / 4);          // 4096 tokens per wave
    const unsigned long long lt = (1ull << lane) - 1ull;

    int v[64];
#pragma unroll
    for (int j = 0; j < 64; ++j) v[j] = idx[seg + j * 64 + lane];

    int my = 0;
#pragma unroll
    for (int j = 0; j < 64; ++j) my += __popcll(__ballot(v[j] == e));

    int my0 = 0;
    if (pass) {
        const int* q = idx0 + seg;
#pragma unroll
        for (int j = 0; j < 64; j += 16) {
            int u[16];
#pragma unroll
            for (int m = 0; m < 16; ++m) u[m] = q[(j + m) * 64 + lane];
#pragma unroll
            for (int m = 0; m < 16; ++m) my0 += __popcll(__ballot(u[m] == e));
        }
    }
    if (lane == 0) { cnt[wid] = my; cnt0[wid] = my0; }
    __syncthreads();

    int running = pass ? (cnt0[0] + cnt0[1] + cnt0[2] + cnt0[3]) : 0;
#pragma unroll
    for (int w2 = 0; w2 < 4; ++w2) if (w2 < wid) running += cnt[w2];

#pragma unroll
    for (int j = 0; j < 64; ++j) {
        bool p = (v[j] == e);
        unsigned long long b = __ballot(p);
        if (p) r[seg + j * 64 + lane] = running + __popcll(b & lt);
        running += __popcll(b);
    }
}

// ---------------- K3: one-hot capacity mask + tail outputs (fused) ----------
__launch_bounds__(256)
__global__ void k_mask_tail(const int* __restrict__ idx0, const int* __restrict__ idx1,
                            const int* __restrict__ r0, const int* __restrict__ r1,
                            const float* __restrict__ probs,
                            float* __restrict__ out, int N, int cap)
{
    int f = blockIdx.x * 256 + threadIdx.x;   // float4 index, total N*32
    int n   = f >> 5;
    int rem = (f & 31) * 4;       // 0..124 within the token's 128 floats
    int k   = rem >> 6;           // 0 or 1
    int e0  = rem & 63;
    int ix = k ? idx1[n] : idx0[n];
    int rr = k ? r1[n]   : r0[n];
    float val = (rr < cap) ? 1.0f : 0.0f;
    float4 o = make_float4(0.f, 0.f, 0.f, 0.f);
    int d = ix - e0;
    if (d >= 0 && d < 4) ((float*)&o)[d] = val;
    *(float4*)(out + (size_t)f * 4) = o;

    size_t base = (size_t)2 * N * E_DIM;
    if (f < 2 * N) {
        int n2 = f >> 1;
        int k2 = f & 1;
        int ix2 = k2 ? idx1[n2] : idx0[n2];
        int rr2 = k2 ? r1[n2]   : r0[n2];
        float p = probs[f];
        out[base + f]         = (rr2 < cap) ? p : 0.0f;   // router_probs_masked
        out[base + 2 * N + f] = (float)ix2;               // top_k_indices
        out[base + 4 * N + f] = (float)rr2;               // final_rank
    }
    if (f == 0) out[base + 6 * N] = (float)cap;           // exp_capacity
}

extern "C" void kernel_launch(void* const* d_in, const int* in_sizes, int n_in,
                              void* d_out, int out_size, void* d_ws, size_t ws_size,
                              hipStream_t stream)
{
    const float* x  = (const float*)d_in[0];
    const float* wg = (const float*)d_in[1];
    const int N = in_sizes[0] / C_DIM;   // 16384 tokens

    // workspace layout (24*N bytes = 384 KB)
    char* ws = (char*)d_ws;
    int*   idx0  = (int*)ws;
    int*   idx1  = idx0 + N;
    float* probs = (float*)(idx1 + N);
    int*   r0    = (int*)(probs + 2 * N);
    int*   r1    = r0 + N;

    float* out = (float*)d_out;

    int cap = (int)((long long)2 * 2 * N / E_DIM);   // TOP_K * EVAL_CAPACITY * N / E
    if (cap < 4) cap = 4;

    k_router<<<N / TB, 256, 0, stream>>>(x, wg, idx0, idx1, probs, N);
    k_scan<<<2 * E_DIM, 256, 0, stream>>>(idx0, idx1, r0, r1, N);
    k_mask_tail<<<(N * 32) / 256, 256, 0, stream>>>(idx0, idx1, r0, r1, probs, out, N, cap);
}

// Round 6
// 338.728 us; speedup vs baseline: 1.9077x; 1.9077x over previous
//
#include <hip/hip_runtime.h>
#include <math.h>

#define C_DIM 2048
#define E_DIM 64
#define TB    32      // tokens per block
#define KQ    512     // k-range per wave (quarter)
#define KT    32      // k per tile
#define STR   36      // LDS row stride in floats (row-to-row bank rotate = 4)
#define SMEMF (4 * TB * STR + 4 * E_DIM * STR)   // 13824 floats = 54 KB

__device__ __forceinline__ float dot16(float4 x0, float4 x1, float4 x2, float4 x3,
                                       float4 w0, float4 w1, float4 w2, float4 w3)
{
    float f;
    f = x0.x * w0.x;
    f = fmaf(x0.y, w0.y, f); f = fmaf(x0.z, w0.z, f); f = fmaf(x0.w, w0.w, f);
    f = fmaf(x1.x, w1.x, f); f = fmaf(x1.y, w1.y, f); f = fmaf(x1.z, w1.z, f);
    f = fmaf(x1.w, w1.w, f);
    f = fmaf(x2.x, w2.x, f); f = fmaf(x2.y, w2.y, f); f = fmaf(x2.z, w2.z, f);
    f = fmaf(x2.w, w2.w, f);
    f = fmaf(x3.x, w3.x, f); f = fmaf(x3.y, w3.y, f); f = fmaf(x3.z, w3.z, f);
    f = fmaf(x3.w, w3.w, f);
    return f;
}

// K1: fp32 register-tiled GEMM (T=4 tokens x E=8 experts per thread, 4-way
// k-split across waves, private per-wave LDS sub-tiles, no main-loop barriers)
// -> cross-wave reduce -> top-4 -> exact fp64 refine -> top-2 + softmax.
__launch_bounds__(256, 2)
__global__ void k_router(const float* __restrict__ x, const float* __restrict__ w,
                         int* __restrict__ idx0, int* __restrict__ idx1,
                         float* __restrict__ probs, int N)
{
    __shared__ __align__(16) float smem[SMEMF];
    const int tid  = threadIdx.x;
    const int lane = tid & 63;
    const int q    = tid >> 6;        // wave = k-quarter
    const int tx   = lane & 7;        // expert slot: experts tx + 8j
    const int ty   = lane >> 3;       // token slot:  tokens  ty + 8i
    const int t0   = blockIdx.x * TB;

    float* xq = smem + q * (TB * STR);                  // this wave's x sub-tile
    float* wq = smem + 4 * TB * STR + q * (E_DIM * STR); // this wave's w sub-tile

    float acc[4][8];
#pragma unroll
    for (int i = 0; i < 4; ++i)
#pragma unroll
        for (int j = 0; j < 8; ++j) acc[i][j] = 0.f;

    const int kq0 = q * KQ;
    const int st  = lane >> 1;          // staging: token row
    const int sh  = (lane & 1) * 16;    // staging: 16-float half

    for (int tile = 0; tile < KQ / KT; ++tile) {
        const int kb = kq0 + tile * KT;
        // stage x sub-tile (32 tokens x 32 k), coalesced 64B per lane
        {
            const float* src = x + (size_t)(t0 + st) * C_DIM + kb + sh;
            float4 a0 = ((const float4*)src)[0];
            float4 a1 = ((const float4*)src)[1];
            float4 a2 = ((const float4*)src)[2];
            float4 a3 = ((const float4*)src)[3];
            float* dst = xq + st * STR + sh;
            ((float4*)dst)[0] = a0; ((float4*)dst)[1] = a1;
            ((float4*)dst)[2] = a2; ((float4*)dst)[3] = a3;
        }
        // stage w sub-tile (64 experts x 32 k), 128B per lane
        {
            const float* src = w + (size_t)lane * C_DIM + kb;
            float4 b0 = ((const float4*)src)[0];
            float4 b1 = ((const float4*)src)[1];
            float4 b2 = ((const float4*)src)[2];
            float4 b3 = ((const float4*)src)[3];
            float4 b4 = ((const float4*)src)[4];
            float4 b5 = ((const float4*)src)[5];
            float4 b6 = ((const float4*)src)[6];
            float4 b7 = ((const float4*)src)[7];
            float* dst = wq + lane * STR;
            ((float4*)dst)[0] = b0; ((float4*)dst)[1] = b1;
            ((float4*)dst)[2] = b2; ((float4*)dst)[3] = b3;
            ((float4*)dst)[4] = b4; ((float4*)dst)[5] = b5;
            ((float4*)dst)[6] = b6; ((float4*)dst)[7] = b7;
        }
        // compute: 8 k4-steps; 12 ds_read_b128 per 128 fmac (conflict-free:
        // lane rows differ by 1 -> bank groups rotate by 4)
#pragma unroll
        for (int s = 0; s < KT / 4; ++s) {
            float4 xf[4], wf[8];
#pragma unroll
            for (int i = 0; i < 4; ++i)
                xf[i] = *(const float4*)&xq[(ty + 8 * i) * STR + s * 4];
#pragma unroll
            for (int j = 0; j < 8; ++j)
                wf[j] = *(const float4*)&wq[(tx + 8 * j) * STR + s * 4];
#pragma unroll
            for (int i = 0; i < 4; ++i)
#pragma unroll
                for (int j = 0; j < 8; ++j) {
                    float a = acc[i][j];
                    a = fmaf(xf[i].x, wf[j].x, a);
                    a = fmaf(xf[i].y, wf[j].y, a);
                    a = fmaf(xf[i].z, wf[j].z, a);
                    a = fmaf(xf[i].w, wf[j].w, a);
                    acc[i][j] = a;
                }
        }
    }

    // ---- cross-wave k-quarter reduction via LDS ----
    __syncthreads();                       // everyone done with sub-tiles
    float*  P    = smem;                   // [4][TB][64] = 8192 floats
    float*  L    = smem + 4 * TB * 64;     // [TB][64]    = 2048 floats
    int*    cand = (int*)(L + TB * 64);    // [TB][4]     = 128 ints
    double* dsum = (double*)(cand + TB * 4); // [TB*4][2] = 256 doubles

#pragma unroll
    for (int i = 0; i < 4; ++i)
#pragma unroll
        for (int j = 0; j < 8; ++j)
            P[q * TB * 64 + (ty + 8 * i) * 64 + tx + 8 * j] = acc[i][j];
    __syncthreads();

    {   // sum 4 quarters: thread = (token t, 8-expert group)
        int t  = tid >> 3;
        int e8 = (tid & 7) * 8;
        float4 sa = make_float4(0.f, 0.f, 0.f, 0.f);
        float4 sb = make_float4(0.f, 0.f, 0.f, 0.f);
#pragma unroll
        for (int qq = 0; qq < 4; ++qq) {
            const float* p = &P[qq * TB * 64 + t * 64 + e8];
            float4 a = ((const float4*)p)[0];
            float4 b = ((const float4*)p)[1];
            sa.x += a.x; sa.y += a.y; sa.z += a.z; sa.w += a.w;
            sb.x += b.x; sb.y += b.y; sb.z += b.z; sb.w += b.w;
        }
        ((float4*)&L[t * 64 + e8])[0] = sa;
        ((float4*)&L[t * 64 + e8])[1] = sb;
    }
    __syncthreads();

    // ---- top-4 per token (noisy fp32, superset of true top-2) ----
    if (tid < TB) {
        const float* row = &L[tid * 64];
        float v0 = -3e38f, v1 = -3e38f, v2 = -3e38f, v3 = -3e38f;
        int   b0 = 64, b1 = 64, b2 = 64, b3 = 64;
        for (int e = 0; e < E_DIM; ++e) {
            float vv = row[e];
            if (vv > v3) {
                if (vv > v0)      { v3=v2;b3=b2; v2=v1;b2=b1; v1=v0;b1=b0; v0=vv;b0=e; }
                else if (vv > v1) { v3=v2;b3=b2; v2=v1;b2=b1; v1=vv;b1=e; }
                else if (vv > v2) { v3=v2;b3=b2; v2=vv;b2=e; }
                else              { v3=vv;b3=e; }
            }
        }
        cand[tid * 4]     = b0;
        cand[tid * 4 + 1] = b1;
        cand[tid * 4 + 2] = b2;
        cand[tid * 4 + 3] = b3;
    }
    __syncthreads();

    // ---- exact refine: 32 tokens x 4 cands x 2 k-halves (absmax-0 numerics) ----
    {
        int t = tid >> 3;
        int c = (tid >> 1) & 3;
        int h = tid & 1;
        int ce = cand[t * 4 + c];
        const float* xp = x + (size_t)(t0 + t) * C_DIM + h * (C_DIM / 2);
        const float* wp = w + (size_t)ce * C_DIM + h * (C_DIM / 2);
        double d0 = 0.0, d1 = 0.0;
#pragma unroll 4
        for (int k = 0; k < C_DIM / 2; k += 32) {
            float4 xa[8], wa[8];
#pragma unroll
            for (int m = 0; m < 8; ++m) xa[m] = *(const float4*)(xp + k + 4 * m);
#pragma unroll
            for (int m = 0; m < 8; ++m) wa[m] = *(const float4*)(wp + k + 4 * m);
            d0 += (double)dot16(xa[0], xa[1], xa[2], xa[3], wa[0], wa[1], wa[2], wa[3]);
            d1 += (double)dot16(xa[4], xa[5], xa[6], xa[7], wa[4], wa[5], wa[6], wa[7]);
        }
        dsum[(t * 4 + c) * 2 + h] = d0 + d1;
    }
    __syncthreads();

    // ---- exact top-2 among candidates (ties: lower expert index) ----
    if (tid < TB) {
        int t = tid;
        double v[4]; int e[4];
#pragma unroll
        for (int c = 0; c < 4; ++c) {
            v[c] = dsum[(t * 4 + c) * 2] + dsum[(t * 4 + c) * 2 + 1];
            e[c] = cand[t * 4 + c];
        }
        int b0 = 0;
#pragma unroll
        for (int c = 1; c < 4; ++c)
            if (v[c] > v[b0] || (v[c] == v[b0] && e[c] < e[b0])) b0 = c;
        int b1 = (b0 == 0) ? 1 : 0;
#pragma unroll
        for (int c = 0; c < 4; ++c) {
            if (c == b0 || c == b1) continue;
            if (v[c] > v[b1] || (v[c] == v[b1] && e[c] < e[b1])) b1 = c;
        }
        int n = t0 + t;
        float p0 = 1.0f / (1.0f + expf((float)(v[b1] - v[b0])));
        idx0[n] = e[b0];
        idx1[n] = e[b1];
        probs[2 * n]     = p0;
        probs[2 * n + 1] = 1.0f - p0;
    }
}

// ---------------- K2: rank scan, 128 blocks x 4 waves, one load round ------
__launch_bounds__(256)
__global__ void k_scan(const int* __restrict__ idx0, const int* __restrict__ idx1,
                       int* __restrict__ r0, int* __restrict__ r1, int N)
{
    const int e    = blockIdx.x >> 1;
    const int pass = blockIdx.x & 1;
    const int tid  = threadIdx.x;
    const int lane = tid & 63;
    const int wid  = tid >> 6;
    __shared__ int cnt[4], cnt0[4];

    const int* idx = pass ? idx1 : idx0;
    int*       r   = pass ? r1   : r0;
    const int  seg = wid * (N / 4);
    const unsigned long long lt = (1ull << lane) - 1ull;

    int v[64];
#pragma unroll
    for (int j = 0; j < 64; ++j) v[j] = idx[seg + j * 64 + lane];

    int my = 0;
#pragma unroll
    for (int j = 0; j < 64; ++j) my += __popcll(__ballot(v[j] == e));

    int my0 = 0;
    if (pass) {
        const int* qq = idx0 + seg;
#pragma unroll
        for (int j = 0; j < 64; j += 16) {
            int u[16];
#pragma unroll
            for (int m = 0; m < 16; ++m) u[m] = qq[(j + m) * 64 + lane];
#pragma unroll
            for (int m = 0; m < 16; ++m) my0 += __popcll(__ballot(u[m] == e));
        }
    }
    if (lane == 0) { cnt[wid] = my; cnt0[wid] = my0; }
    __syncthreads();

    int running = pass ? (cnt0[0] + cnt0[1] + cnt0[2] + cnt0[3]) : 0;
#pragma unroll
    for (int w2 = 0; w2 < 4; ++w2) if (w2 < wid) running += cnt[w2];

#pragma unroll
    for (int j = 0; j < 64; ++j) {
        bool p = (v[j] == e);
        unsigned long long b = __ballot(p);
        if (p) r[seg + j * 64 + lane] = running + __popcll(b & lt);
        running += __popcll(b);
    }
}

// ---------------- K3: one-hot capacity mask + tail outputs (fused) ----------
__launch_bounds__(256)
__global__ void k_mask_tail(const int* __restrict__ idx0, const int* __restrict__ idx1,
                            const int* __restrict__ r0, const int* __restrict__ r1,
                            const float* __restrict__ probs,
                            float* __restrict__ out, int N, int cap)
{
    int f = blockIdx.x * 256 + threadIdx.x;
    int n   = f >> 5;
    int rem = (f & 31) * 4;
    int k   = rem >> 6;
    int e0  = rem & 63;
    int ix = k ? idx1[n] : idx0[n];
    int rr = k ? r1[n]   : r0[n];
    float val = (rr < cap) ? 1.0f : 0.0f;
    float4 o = make_float4(0.f, 0.f, 0.f, 0.f);
    int d = ix - e0;
    if (d >= 0 && d < 4) ((float*)&o)[d] = val;
    *(float4*)(out + (size_t)f * 4) = o;

    size_t base = (size_t)2 * N * E_DIM;
    if (f < 2 * N) {
        int n2 = f >> 1;
        int k2 = f & 1;
        int ix2 = k2 ? idx1[n2] : idx0[n2];
        int rr2 = k2 ? r1[n2]   : r0[n2];
        float p = probs[f];
        out[base + f]         = (rr2 < cap) ? p : 0.0f;
        out[base + 2 * N + f] = (float)ix2;
        out[base + 4 * N + f] = (float)rr2;
    }
    if (f == 0) out[base + 6 * N] = (float)cap;
}

extern "C" void kernel_launch(void* const* d_in, const int* in_sizes, int n_in,
                              void* d_out, int out_size, void* d_ws, size_t ws_size,
                              hipStream_t stream)
{
    const float* x  = (const float*)d_in[0];
    const float* wg = (const float*)d_in[1];
    const int N = in_sizes[0] / C_DIM;   // 16384 tokens

    char* ws = (char*)d_ws;
    int*   idx0  = (int*)ws;
    int*   idx1  = idx0 + N;
    float* probs = (float*)(idx1 + N);
    int*   r0    = (int*)(probs + 2 * N);
    int*   r1    = r0 + N;

    float* out = (float*)d_out;

    int cap = (int)((long long)2 * 2 * N / E_DIM);
    if (cap < 4) cap = 4;

    k_router<<<N / TB, 256, 0, stream>>>(x, wg, idx0, idx1, probs, N);
    k_scan<<<2 * E_DIM, 256, 0, stream>>>(idx0, idx1, r0, r1, N);
    k_mask_tail<<<(N * 32) / 256, 256, 0, stream>>>(idx0, idx1, r0, r1, probs, out, N, cap);
}